// Round 5
// baseline (503.509 us; speedup 1.0000x reference)
//
#include <hip/hip_runtime.h>
#include <stdint.h>

#define B_ 8
#define C_ 256
#define N_ 4096
#define M_ 4096
#define NT 64
#define MT 32
#define MITER (M_ / MT)   // 128
#define PP 40             // sP pitch (32 + 8 pad) halves
#define L2E 1.44269504f

typedef _Float16 f16x8 __attribute__((ext_vector_type(8)));
typedef _Float16 f16x4 __attribute__((ext_vector_type(4)));
typedef float f32x4 __attribute__((ext_vector_type(4)));

__device__ __forceinline__ void async16(const _Float16* g, _Float16* l) {
    __builtin_amdgcn_global_load_lds(
        (const __attribute__((address_space(1))) void*)g,
        (__attribute__((address_space(3))) void*)l, 16, 0, 0);
}

// fused pre-pass: blocks [0,2048) transpose xs -> kt [B,M,C] fp16;
//                 blocks [2048,10240) convert ys -> vb [B,C,M] fp16
__global__ __launch_bounds__(256) void kPre(const float* __restrict__ xs,
                                            const float* __restrict__ ys,
                                            _Float16* __restrict__ kt,
                                            _Float16* __restrict__ vb) {
    int bx = blockIdx.x;
    int t = threadIdx.x;
    if (bx < 2048) {
        __shared__ float tile[64][65];
        int b = bx >> 8, rem = bx & 255;
        int c0 = (rem >> 6) * 64, m0 = (rem & 63) * 64;
        int cl = t >> 4, m4 = (t & 15) * 4;
#pragma unroll
        for (int i = 0; i < 4; i++) {
            int c = c0 + cl + i * 16;
            const float4 v = *(const float4*)(xs + ((size_t)(b * C_ + c) * M_) + m0 + m4);
            tile[m4 + 0][cl + i * 16] = v.x;
            tile[m4 + 1][cl + i * 16] = v.y;
            tile[m4 + 2][cl + i * 16] = v.z;
            tile[m4 + 3][cl + i * 16] = v.w;
        }
        __syncthreads();
        int ml = t >> 4, c4 = (t & 15) * 4;
#pragma unroll
        for (int i = 0; i < 4; i++) {
            int m = m0 + ml + i * 16;
            f16x4 o;
            o[0] = (_Float16)tile[ml + i * 16][c4 + 0];
            o[1] = (_Float16)tile[ml + i * 16][c4 + 1];
            o[2] = (_Float16)tile[ml + i * 16][c4 + 2];
            o[3] = (_Float16)tile[ml + i * 16][c4 + 3];
            *(f16x4*)(kt + ((size_t)(b * M_ + m) * C_) + c0 + c4) = o;
        }
    } else {
        size_t i = ((size_t)(bx - 2048) * 256 + t) * 4;
        float4 v = *(const float4*)(ys + i);
        f16x4 o;
        o[0] = (_Float16)v.x; o[1] = (_Float16)v.y;
        o[2] = (_Float16)v.z; o[3] = (_Float16)v.w;
        *(f16x4*)(vb + i) = o;
    }
}

// Producer/consumer wave-specialized flash attention, MT=32.
// 512-thread blocks (8 waves), 2 blocks/CU (LDS ~71.5 KB) -> 16 waves/CU, 4/SIMD.
// Waves 0-3 (producers): QK^T + online softmax + P publish, 16 n-rows each.
//   Q is re-read from sQ per ks step (not register-resident) to keep the
//   producer/consumer register UNION <= 128 VGPR (no spills at min-waves=4).
// Waves 4-7 (consumers): O-rescale + PV + V-loads, 64 channels each.
// Each SIMD hosts 2 producers + 2 consumers -> QK/softmax overlaps PV across
// wave roles. Sync: barrier A (vmcnt0: K landed, P visible), work, barrier B
// (lgkm0: sP reads done), phase-2 P/alpha/flag publish.
__global__ __launch_bounds__(512, 4) void kAttn(const float* __restrict__ h,
                                                const _Float16* __restrict__ kt,
                                                const _Float16* __restrict__ vb,
                                                float* __restrict__ out) {
    __shared__ _Float16 sK[2][MT * 256];     // 32 KB, rows 512B XOR-swizzled by (row&31)
    __shared__ _Float16 sQ[NT * 256];        // 32 KB, same swizzle
    __shared__ _Float16 sP[NT * PP];         // 5 KB
    __shared__ float sAlpha[NT];
    __shared__ float sL[NT];
    __shared__ int sFlag[2];

    const int t = threadIdx.x;
    const int w = t >> 6, lane = t & 63, quad = lane >> 4, l15 = lane & 15;
    const int b = blockIdx.x & 7;            // batch -> XCD (kt[b]+vb[b] = 4MB L2-resident)
    const int n0 = (blockIdx.x >> 3) * NT;
    const bool prod = (w < 4);
    const int pw = w & 3;
    const int nb = pw * 16;                  // producer n-strip
    const int cb = pw * 64;                  // consumer channel strip

    const _Float16* srcKb = kt + (size_t)b * M_ * C_;
    const _Float16* srcVb = vb + (size_t)b * C_ * M_;

    if (t == 0) { sFlag[0] = 0; sFlag[1] = 0; }

    // ---- prologue: issue K0 -> sK[0]; stage Q (transposed+swizzled) -> sQ ----
#pragma unroll
    for (int j = 0; j < 2; j++) {
        int row = w * 4 + j * 2 + (lane >> 5);
        int logi = (lane & 31) ^ (row & 31);
        async16(srcKb + (size_t)row * C_ + logi * 8, &sK[0][(w * 4 + j * 2) * 256]);
    }
    {
        int cl = t >> 4;                 // 0..31
        int n4 = (t & 15) * 4;           // 0..60
#pragma unroll
        for (int i = 0; i < 8; i++) {
            int c = i * 32 + cl;
            const float4 v = *(const float4*)(h + ((size_t)(b * C_ + c) * N_) + n0 + n4);
            float xv[4] = {v.x, v.y, v.z, v.w};
#pragma unroll
            for (int j = 0; j < 4; j++) {
                int row = n4 + j;
                sQ[row * 256 + (((c >> 3) ^ (row & 31)) << 3) + (c & 7)] = (_Float16)xv[j];
            }
        }
    }

    f32x4 o[4][4];                       // consumers: 64c x 64n
#pragma unroll
    for (int i = 0; i < 4; i++)
#pragma unroll
        for (int j = 0; j < 4; j++)
            o[i][j] = (f32x4){0.f, 0.f, 0.f, 0.f};
    f16x8 vf[4];                         // consumers: V(it) fragments (k=32)
    float mst = -3.0e38f, lp = 0.f;      // producers
    float al = 1.0f;
    f32x4 s4[2];                         // producers: S^T then P

    for (int it = 0; it <= MITER; it++) {
        const int cur = it & 1, nxt = cur ^ 1;
        // ---- barrier A: K(it) landed; V(it-1) landed; P(it-1)/alpha/flag visible ----
        asm volatile("s_waitcnt vmcnt(0) lgkmcnt(0)" ::: "memory");
        __builtin_amdgcn_s_barrier();

        // issue K(it+1) into the buffer QK(it-1) finished reading (all waves)
        if (it < MITER - 1) {
            const _Float16* srcK = srcKb + (size_t)(it + 1) * MT * C_;
#pragma unroll
            for (int j = 0; j < 2; j++) {
                int row = w * 4 + j * 2 + (lane >> 5);
                int logi = (lane & 31) ^ (row & 31);
                async16(srcK + (size_t)row * C_ + logi * 8, &sK[nxt][(w * 4 + j * 2) * 256]);
            }
        }

        if (prod) {
            if (it < MITER) {
                // ---- S^T(it) = K·Q^T : s4[mt][r] = S^T[m=mt*16+quad*4+r][n=nb+l15] ----
                s4[0] = (f32x4){0.f, 0.f, 0.f, 0.f};
                s4[1] = (f32x4){0.f, 0.f, 0.f, 0.f};
                const int qrow = nb + l15;
                __builtin_amdgcn_s_setprio(1);
#pragma unroll
                for (int ks = 0; ks < 8; ks++) {
                    f16x8 qk = *(const f16x8*)(&sQ[qrow * 256 + ((((ks << 2) + quad) ^ (qrow & 31)) << 3)]);
#pragma unroll
                    for (int mt = 0; mt < 2; mt++) {
                        int krow = mt * 16 + l15;
                        f16x8 bk = *(const f16x8*)(&sK[cur][krow * 256 + ((((ks << 2) + quad) ^ (krow & 31)) << 3)]);
                        s4[mt] = __builtin_amdgcn_mfma_f32_16x16x32_f16(bk, qk, s4[mt], 0, 0, 0);
                    }
                }
                __builtin_amdgcn_s_setprio(0);

                // ---- online softmax for row n = nb+l15 (8 vals + 2 shuffles) ----
                float rowmax = fmaxf(fmaxf(fmaxf(s4[0][0], s4[0][1]), fmaxf(s4[0][2], s4[0][3])),
                                     fmaxf(fmaxf(s4[1][0], s4[1][1]), fmaxf(s4[1][2], s4[1][3])));
                rowmax = fmaxf(rowmax, __shfl_xor(rowmax, 16, 64));
                rowmax = fmaxf(rowmax, __shfl_xor(rowmax, 32, 64));
                al = 1.0f;
                if (rowmax > mst) {
                    al = exp2f((mst - rowmax) * L2E);
                    mst = rowmax;
                }
                const float mb = mst * L2E;
                float psum = 0.f;
#pragma unroll
                for (int mt = 0; mt < 2; mt++)
#pragma unroll
                    for (int r = 0; r < 4; r++) {
                        float p = exp2f(s4[mt][r] * L2E - mb);
                        s4[mt][r] = p;
                        psum += p;
                    }
                lp = lp * al + psum;
            }
        } else {
            // ---- consumers: rescale O by alpha(it-1), PV(it-1), issue V(it) ----
            if (it > 0 && sFlag[nxt]) {          // flag(it-1) lives in slot (it-1)&1
                float av[4];
#pragma unroll
                for (int nt = 0; nt < 4; nt++) av[nt] = sAlpha[nt * 16 + l15];
#pragma unroll
                for (int ct = 0; ct < 4; ct++)
#pragma unroll
                    for (int nt = 0; nt < 4; nt++) {
                        o[ct][nt][0] *= av[nt];
                        o[ct][nt][1] *= av[nt];
                        o[ct][nt][2] *= av[nt];
                        o[ct][nt][3] *= av[nt];
                    }
            }
            if (it > 0) {
                __builtin_amdgcn_s_setprio(1);
#pragma unroll
                for (int nt = 0; nt < 4; nt++) {
                    f16x8 bp = *(const f16x8*)(sP + (nt * 16 + l15) * PP + quad * 8);
#pragma unroll
                    for (int ct = 0; ct < 4; ct++)
                        o[ct][nt] = __builtin_amdgcn_mfma_f32_16x16x32_f16(vf[ct], bp, o[ct][nt], 0, 0, 0);
                }
                __builtin_amdgcn_s_setprio(0);
            }
            if (it < MITER) {
                int m0i = it * MT;
#pragma unroll
                for (int ct = 0; ct < 4; ct++) {
                    int vrow = cb + ct * 16 + l15;
                    vf[ct] = *(const f16x8*)(srcVb + (size_t)vrow * M_ + m0i + quad * 8);
                }
            }
        }

        // ---- barrier B: consumers done reading sP(it-1)/sAlpha; producers done sK[cur] ----
        asm volatile("s_waitcnt lgkmcnt(0)" ::: "memory");
        __builtin_amdgcn_s_barrier();

        // ---- phase 2: producers publish P(it)/alpha(it)/flag(it) ----
        if (prod && it < MITER) {
            int prow = nb + l15;
#pragma unroll
            for (int mt = 0; mt < 2; mt++) {
                f16x4 pk;
                pk[0] = (_Float16)s4[mt][0];
                pk[1] = (_Float16)s4[mt][1];
                pk[2] = (_Float16)s4[mt][2];
                pk[3] = (_Float16)s4[mt][3];
                *(f16x4*)(&sP[prow * PP + mt * 16 + quad * 4]) = pk;
            }
            if (quad == 0) {
                sAlpha[prow] = al;
                if (al != 1.0f) atomicOr(&sFlag[cur], 1);
            }
            if (t == 0) sFlag[nxt] = 0;  // re-arm for flag(it+1); flag(it-1) reads done
        }
    }

    // ---- epilogue ----
    if (prod) {
        lp += __shfl_xor(lp, 16, 64);
        lp += __shfl_xor(lp, 32, 64);
        if (quad == 0) sL[nb + l15] = lp;
    }
    __syncthreads();
    if (!prod) {
        float linv[4];
#pragma unroll
        for (int nt = 0; nt < 4; nt++) linv[nt] = 1.0f / sL[nt * 16 + l15];
#pragma unroll
        for (int ct = 0; ct < 4; ct++)
#pragma unroll
            for (int nt = 0; nt < 4; nt++)
#pragma unroll
                for (int r = 0; r < 4; r++) {
                    int c = cb + ct * 16 + quad * 4 + r;
                    out[((size_t)(b * C_ + c)) * N_ + n0 + nt * 16 + l15] = o[ct][nt][r] * linv[nt];
                }
    }
}

extern "C" void kernel_launch(void* const* d_in, const int* in_sizes, int n_in,
                              void* d_out, int out_size, void* d_ws, size_t ws_size,
                              hipStream_t stream) {
    const float* h  = (const float*)d_in[0];
    const float* xs = (const float*)d_in[1];
    const float* ys = (const float*)d_in[2];
    float* out = (float*)d_out;

    _Float16* kt  = (_Float16*)d_ws;                    // [B,M,C] fp16: 16 MB
    _Float16* vbb = kt + (size_t)B_ * M_ * C_;          // [B,C,M] fp16: 16 MB

    kPre<<<dim3(2048 + 8192), 256, 0, stream>>>(xs, ys, kt, vbb);
    kAttn<<<dim3(B_ * (N_ / NT)), 512, 0, stream>>>(h, kt, vbb, out);
}